// Round 1
// baseline (235.235 us; speedup 1.0000x reference)
//
#include <hip/hip_runtime.h>

using f32x4  = __attribute__((ext_vector_type(4))) float;
using bf16x8 = __attribute__((ext_vector_type(8))) short;

#define DEV static __device__ __forceinline__

DEV unsigned short f2bf(float f){
  unsigned u = __float_as_uint(f);
  unsigned r = (u + 0x7FFFu + ((u >> 16) & 1u)) >> 16;
  return (unsigned short)r;
}

// ---------------- K0: weight prep ----------------
__global__ __launch_bounds__(256) void prep_kernel(
    const float* __restrict__ fp_w, const float* __restrict__ q_w,
    const float* __restrict__ k_w, const float* __restrict__ v_w,
    const float* __restrict__ o_w, const float* __restrict__ fu_w,
    const float* __restrict__ pr1_w, const float* __restrict__ s0_w,
    const float* __restrict__ s1_w, const float* __restrict__ pr2_w,
    const float* __restrict__ rg_w,
    unsigned short* __restrict__ fpw_bf, unsigned short* __restrict__ wcat_bf,
    float* __restrict__ o_wT, float* __restrict__ fu_wT, float* __restrict__ pr1_wT,
    float* __restrict__ s0_wT, float* __restrict__ s1_wT0, float* __restrict__ s1_wT1,
    float* __restrict__ pr2_wT, float* __restrict__ rg_wT){
  int i = blockIdx.x * blockDim.x + threadIdx.x;
  int stride = gridDim.x * blockDim.x;
  for (int idx = i; idx < 128 * 2048; idx += stride) fpw_bf[idx] = f2bf(fp_w[idx]);
  for (int idx = i; idx < 384 * 128; idx += stride){
    int c = idx >> 7, k = idx & 127;
    float v;
    if (c < 128)      v = q_w[c * 128 + k] * 0.25f;   // fold 1/sqrt(hd)
    else if (c < 256) v = k_w[(c - 128) * 128 + k];
    else              v = v_w[(c - 256) * 128 + k];
    wcat_bf[idx] = f2bf(v);
  }
  for (int idx = i; idx < 128 * 128; idx += stride){
    int k = idx >> 7, c = idx & 127;
    o_wT[idx]   = o_w[c * 128 + k];
    fu_wT[idx]  = fu_w[c * 128 + k];
    pr1_wT[idx] = pr1_w[c * 128 + k];
    s0_wT[idx]  = s0_w[c * 128 + k];             // (o,i,1)
    s1_wT0[idx] = s1_w[(c * 128 + k) * 2 + 0];   // (o,i,2)
    s1_wT1[idx] = s1_w[(c * 128 + k) * 2 + 1];
  }
  for (int idx = i; idx < 128 * 24; idx += stride){
    int k = idx / 24, c = idx % 24;
    pr2_wT[idx] = pr2_w[c * 128 + k];
    rg_wT[idx]  = rg_w[c * 128 + k];
  }
}

// ---------------- K1: temporal conv + bn + relu -> f bf16 (4096 x 2048) ----
__global__ __launch_bounds__(256) void conv_kernel(
    const float* __restrict__ x, const float* __restrict__ tc_w,
    const float* __restrict__ tc_b, const float* __restrict__ bn_g,
    const float* __restrict__ bn_b, unsigned short* __restrict__ f){
  int lane = threadIdx.x & 63;          // t = lane (T = 64)
  int w = threadIdx.x >> 6;
  int row = blockIdx.x * 4 + w;         // 0..4095 = b*2048+n
  int b = row >> 11, n = row & 2047;
  float xv = x[(size_t)(b * 64 + lane) * 2048 + n];
  float xm = __shfl_up(xv, 1, 64);   if (lane == 0)  xm = 0.f;
  float xp = __shfl_down(xv, 1, 64); if (lane == 63) xp = 0.f;
  const float inv = rsqrtf(1.0f + 1e-5f);
  unsigned short* frow = f + (size_t)row * 2048;
  #pragma unroll
  for (int c = 0; c < 32; c++){
    float y = xm * tc_w[c * 3 + 0] + xv * tc_w[c * 3 + 1] + xp * tc_w[c * 3 + 2] + tc_b[c];
    y = y * inv * bn_g[c] + bn_b[c];
    frow[c * 64 + lane] = f2bf(fmaxf(y, 0.f));
  }
}

// ---------------- K2: feats = relu(LN(f @ fp_w^T + b)) -> bf16 (4096 x 128)
__global__ __launch_bounds__(256) void feat_kernel(
    const unsigned short* __restrict__ f, const unsigned short* __restrict__ fpw,
    const float* __restrict__ fp_b, const float* __restrict__ ln_g,
    const float* __restrict__ ln_b, unsigned short* __restrict__ feats){
  __shared__ float pre[16][128];
  __shared__ float stat[16][2];
  int t = threadIdx.x;
  int lane = t & 63, w = t >> 6;
  int l15 = lane & 15, g = lane >> 4;
  int row0 = blockIdx.x * 16;
  int c0 = w * 32;
  f32x4 acc0 = {0.f,0.f,0.f,0.f}, acc1 = {0.f,0.f,0.f,0.f};
  const unsigned short* arow = f   + (size_t)(row0 + l15) * 2048 + g * 8;
  const unsigned short* b0p  = fpw + (size_t)(c0 + l15) * 2048 + g * 8;
  const unsigned short* b1p  = fpw + (size_t)(c0 + 16 + l15) * 2048 + g * 8;
  #pragma unroll 4
  for (int k = 0; k < 2048; k += 32){
    bf16x8 a  = *(const bf16x8*)(arow + k);
    bf16x8 b0 = *(const bf16x8*)(b0p + k);
    bf16x8 b1 = *(const bf16x8*)(b1p + k);
    acc0 = __builtin_amdgcn_mfma_f32_16x16x32_bf16(a, b0, acc0, 0, 0, 0);
    acc1 = __builtin_amdgcn_mfma_f32_16x16x32_bf16(a, b1, acc1, 0, 0, 0);
  }
  #pragma unroll
  for (int r = 0; r < 4; r++){
    int rr = g * 4 + r;
    pre[rr][c0 + l15]      = acc0[r] + fp_b[c0 + l15];
    pre[rr][c0 + 16 + l15] = acc1[r] + fp_b[c0 + 16 + l15];
  }
  __syncthreads();
  {
    int r = t >> 4, j = t & 15;
    float s = 0.f, ss = 0.f;
    #pragma unroll
    for (int q = 0; q < 8; q++){ float v = pre[r][j + q * 16]; s += v; ss += v * v; }
    #pragma unroll
    for (int m = 1; m < 16; m <<= 1){ s += __shfl_xor(s, m, 64); ss += __shfl_xor(ss, m, 64); }
    if (j == 0){
      float mean = s * (1.f / 128.f);
      stat[r][0] = mean;
      stat[r][1] = rsqrtf(ss * (1.f / 128.f) - mean * mean + 1e-5f);
    }
  }
  __syncthreads();
  {
    int r = t >> 4, j = t & 15;
    float mean = stat[r][0], rstd = stat[r][1];
    bf16x8 outv;
    #pragma unroll
    for (int q = 0; q < 8; q++){
      int c = j * 8 + q;
      float v = (pre[r][c] - mean) * rstd * ln_g[c] + ln_b[c];
      outv[q] = (short)f2bf(fmaxf(v, 0.f));
    }
    *(bf16x8*)(feats + (size_t)(row0 + r) * 128 + j * 8) = outv;
  }
}

// ---------------- K3: q/k/v projection -------------------------------------
__global__ __launch_bounds__(256) void qkv_kernel(
    const unsigned short* __restrict__ feats, const unsigned short* __restrict__ wcat,
    const float* __restrict__ q_b, const float* __restrict__ k_b,
    const float* __restrict__ v_b, unsigned short* __restrict__ qo,
    unsigned short* __restrict__ ko, unsigned short* __restrict__ vT){
  int t = threadIdx.x, lane = t & 63, w = t >> 6;
  int l15 = lane & 15, g = lane >> 4;
  int row0 = blockIdx.x * 16;
  int c0 = w * 96;
  f32x4 acc[6];
  #pragma unroll
  for (int i = 0; i < 6; i++) acc[i] = (f32x4){0.f,0.f,0.f,0.f};
  const unsigned short* arow = feats + (size_t)(row0 + l15) * 128 + g * 8;
  #pragma unroll
  for (int k = 0; k < 128; k += 32){
    bf16x8 a = *(const bf16x8*)(arow + k);
    #pragma unroll
    for (int ni = 0; ni < 6; ni++){
      bf16x8 bb = *(const bf16x8*)(wcat + (size_t)(c0 + ni * 16 + l15) * 128 + g * 8 + k);
      acc[ni] = __builtin_amdgcn_mfma_f32_16x16x32_bf16(a, bb, acc[ni], 0, 0, 0);
    }
  }
  #pragma unroll
  for (int ni = 0; ni < 6; ni++){
    int c = c0 + ni * 16 + l15;
    int mat = c >> 7, cm = c & 127;
    int h = cm >> 4, d = cm & 15;
    float bias = (mat == 0) ? q_b[cm] * 0.25f : (mat == 1 ? k_b[cm] : v_b[cm]);
    #pragma unroll
    for (int r = 0; r < 4; r++){
      int row = row0 + g * 4 + r;
      int b = row >> 11, n = row & 2047;
      unsigned short bv = f2bf(acc[ni][r] + bias);
      int bh = b * 8 + h;
      if (mat == 0)      qo[((size_t)bh * 2048 + n) * 16 + d] = bv;
      else if (mat == 1) ko[((size_t)bh * 2048 + n) * 16 + d] = bv;
      else               vT[((size_t)bh * 16 + d) * 2048 + n] = bv;
    }
  }
}

// ---------------- K4: fused attention (adj read once, both batches) --------
__global__ __launch_bounds__(256) void attn_kernel(
    const unsigned short* __restrict__ qo, const unsigned short* __restrict__ ko,
    const unsigned short* __restrict__ vT, const float* __restrict__ adj,
    float* __restrict__ go){
  __shared__ unsigned short Pls[4][1024];
  int t = threadIdx.x, lane = t & 63, w = t >> 6;
  int l15 = lane & 15, g = lane >> 4;
  int h = blockIdx.x >> 5;
  int row0 = (blockIdx.x & 31) * 64 + w * 16;
  const bf16x8 zf = {0,0,0,0,0,0,0,0};
  bf16x8 qf[2];
  #pragma unroll
  for (int b = 0; b < 2; b++){
    if (g < 2) qf[b] = *(const bf16x8*)(qo + ((size_t)(b * 8 + h) * 2048 + row0 + l15) * 16 + g * 8);
    else       qf[b] = zf;
  }
  f32x4 accv[2] = {{0.f,0.f,0.f,0.f},{0.f,0.f,0.f,0.f}};
  float rs[2][4] = {{0,0,0,0},{0,0,0,0}};
  const float* adjbase = adj + ((size_t)h * 2048 + row0) * 2048;
  unsigned short* P = Pls[w];
  for (int m0 = 0; m0 < 2048; m0 += 64){
    float adjv[4][4];
    #pragma unroll
    for (int s = 0; s < 4; s++)
      #pragma unroll
      for (int r = 0; r < 4; r++)
        adjv[s][r] = adjbase[(size_t)(g * 4 + r) * 2048 + m0 + s * 16 + l15];
    #pragma unroll
    for (int b = 0; b < 2; b++){
      int bh = b * 8 + h;
      const unsigned short* kbase = ko + (size_t)bh * 2048 * 16;
      f32x4 sf[4];
      #pragma unroll
      for (int s = 0; s < 4; s++){
        bf16x8 kf;
        if (g < 2) kf = *(const bf16x8*)(kbase + (size_t)(m0 + s * 16 + l15) * 16 + g * 8);
        else       kf = zf;
        f32x4 z4 = {0.f,0.f,0.f,0.f};
        sf[s] = __builtin_amdgcn_mfma_f32_16x16x32_bf16(qf[b], kf, z4, 0, 0, 0);
      }
      #pragma unroll
      for (int s = 0; s < 4; s++){
        #pragma unroll
        for (int r = 0; r < 4; r++){
          float p = __expf(sf[s][r] + adjv[s][r]);   // scores tiny: no-max softmax
          rs[b][r] += p;
          int rowl = g * 4 + r;
          int col = s * 16 + l15;
          int chunk = col >> 3;
          P[rowl * 64 + (((chunk ^ (rowl & 7)) << 3) | (col & 7))] = f2bf(p);
        }
      }
      const unsigned short* vbase = vT + (size_t)bh * 16 * 2048;
      #pragma unroll
      for (int half = 0; half < 2; half++){
        int chunk = half * 4 + g;
        bf16x8 af = *(const bf16x8*)(P + l15 * 64 + ((chunk ^ (l15 & 7)) << 3));
        bf16x8 vf = *(const bf16x8*)(vbase + (size_t)l15 * 2048 + m0 + half * 32 + g * 8);
        accv[b] = __builtin_amdgcn_mfma_f32_16x16x32_bf16(af, vf, accv[b], 0, 0, 0);
      }
    }
  }
  #pragma unroll
  for (int b = 0; b < 2; b++){
    #pragma unroll
    for (int r = 0; r < 4; r++){
      float s = rs[b][r];
      #pragma unroll
      for (int m = 1; m < 16; m <<= 1) s += __shfl_xor(s, m, 64);
      int row = row0 + g * 4 + r;
      go[((size_t)b * 2048 + row) * 128 + h * 16 + l15] = accv[b][r] / s;
    }
  }
}

// ---------------- K6: o-proj + s0/s1 convs + interp + fusion + tail --------
__global__ __launch_bounds__(256) void tail_kernel(
    const float* __restrict__ go, const float* __restrict__ x,
    const float* __restrict__ o_wT, const float* __restrict__ o_b,
    const float* __restrict__ s0_wT, const float* __restrict__ s0_b,
    const float* __restrict__ s0_g, const float* __restrict__ s0_bb,
    const float* __restrict__ s1_wT0, const float* __restrict__ s1_wT1,
    const float* __restrict__ s1_b, const float* __restrict__ s1_g,
    const float* __restrict__ s1_bb, const float* __restrict__ fw,
    const float* __restrict__ fu_wT, const float* __restrict__ fu_b,
    const float* __restrict__ fu_g, const float* __restrict__ fu_bb,
    const float* __restrict__ pr1_wT, const float* __restrict__ pr1_b,
    const float* __restrict__ pr_g, const float* __restrict__ pr_bb,
    const float* __restrict__ pr2_wT, const float* __restrict__ pr2_b,
    const float* __restrict__ rg_wT, const float* __restrict__ rg_b,
    float* __restrict__ out){
  __shared__ float go_s[18][128];
  __shared__ float gf_s[18][128];
  __shared__ float f1_s[17][128];
  __shared__ float fu_in[16][128];
  __shared__ float pre_s[16][128];
  __shared__ float ff_s[16][128];
  __shared__ float h_s[16][128];
  __shared__ float stat[16][2];
  int t = threadIdx.x;
  int b = blockIdx.x >> 7;
  int n0 = (blockIdx.x & 127) * 16;
  for (int e = t; e < 18 * 128; e += 256){
    int lr = e >> 7, c = e & 127;
    int gn = n0 - 1 + lr;
    go_s[lr][c] = (gn >= 0 && gn < 2048) ? go[((size_t)b * 2048 + gn) * 128 + c] : 0.f;
  }
  __syncthreads();
  int c = t & 127, half = t >> 7;
  const float bninv = rsqrtf(1.0f + 1e-5f);
  { // gf = go @ o_w^T + o_b  (18 rows incl halo; zero outside [0,2048))
    float acc[9];
    float bias = o_b[c];
    #pragma unroll
    for (int i = 0; i < 9; i++) acc[i] = bias;
    for (int k = 0; k < 128; k++){
      float wv = o_wT[k * 128 + c];
      #pragma unroll
      for (int i = 0; i < 9; i++) acc[i] += go_s[half * 9 + i][k] * wv;
    }
    #pragma unroll
    for (int i = 0; i < 9; i++){
      int lr = half * 9 + i;
      int gn = n0 - 1 + lr;
      gf_s[lr][c] = (gn >= 0 && gn < 2048) ? acc[i] : 0.f;
    }
  }
  __syncthreads();
  { // f1[t'] = relu(bn1(S1_0 @ gf[t'-1] + S1_1 @ gf[t'] + b)), t' = n0..n0+16
    float acc[9];
    float bias = s1_b[c];
    #pragma unroll
    for (int i = 0; i < 9; i++) acc[i] = bias;
    for (int k = 0; k < 128; k++){
      float w0 = s1_wT0[k * 128 + c], w1 = s1_wT1[k * 128 + c];
      #pragma unroll
      for (int i = 0; i < 9; i++){
        if (half == 0 || i < 8)
          acc[i] += gf_s[half * 9 + i][k] * w0 + gf_s[half * 9 + i + 1][k] * w1;
      }
    }
    float sc = s1_g[c] * bninv, bb = s1_bb[c];
    #pragma unroll
    for (int i = 0; i < 9; i++){
      int lr = half * 9 + i;
      if (lr < 17) f1_s[lr][c] = fmaxf(acc[i] * sc + bb, 0.f);
    }
  }
  __syncthreads();
  { // fused = a0*f0 + a1*interp(f1)
    float acc[8];
    float bias = s0_b[c];
    #pragma unroll
    for (int i = 0; i < 8; i++) acc[i] = bias;
    for (int k = 0; k < 128; k++){
      float wv = s0_wT[k * 128 + c];
      #pragma unroll
      for (int i = 0; i < 8; i++) acc[i] += gf_s[half * 8 + i + 1][k] * wv;
    }
    float e0 = __expf(fw[0]), e1 = __expf(fw[1]);
    float a0 = e0 / (e0 + e1), a1 = e1 / (e0 + e1);
    float sc = s0_g[c] * bninv, bb = s0_bb[c];
    #pragma unroll
    for (int i = 0; i < 8; i++){
      int lr = half * 8 + i;
      int n = n0 + lr;
      float f0 = fmaxf(acc[i] * sc + bb, 0.f);
      float wn = (n + 0.5f) * (1.0f / 2048.0f);
      fu_in[lr][c] = a0 * f0 + a1 * ((1.f - wn) * f1_s[lr][c] + wn * f1_s[lr + 1][c]);
    }
  }
  __syncthreads();
  { // fu linear
    float acc[8];
    float bias = fu_b[c];
    #pragma unroll
    for (int i = 0; i < 8; i++) acc[i] = bias;
    for (int k = 0; k < 128; k++){
      float wv = fu_wT[k * 128 + c];
      #pragma unroll
      for (int i = 0; i < 8; i++) acc[i] += fu_in[half * 8 + i][k] * wv;
    }
    #pragma unroll
    for (int i = 0; i < 8; i++) pre_s[half * 8 + i][c] = acc[i];
  }
  __syncthreads();
  { // LN -> ff
    int r = t >> 4, j = t & 15;
    float s = 0.f, ss = 0.f;
    #pragma unroll
    for (int q = 0; q < 8; q++){ float v = pre_s[r][j + q * 16]; s += v; ss += v * v; }
    #pragma unroll
    for (int m = 1; m < 16; m <<= 1){ s += __shfl_xor(s, m, 64); ss += __shfl_xor(ss, m, 64); }
    if (j == 0){ float mean = s * (1.f / 128.f); stat[r][0] = mean;
                 stat[r][1] = rsqrtf(ss * (1.f / 128.f) - mean * mean + 1e-5f); }
  }
  __syncthreads();
  {
    int r = t >> 4, j = t & 15;
    float mean = stat[r][0], rstd = stat[r][1];
    #pragma unroll
    for (int q = 0; q < 8; q++){
      int cc = j * 8 + q;
      ff_s[r][cc] = fmaxf((pre_s[r][cc] - mean) * rstd * fu_g[cc] + fu_bb[cc], 0.f);
    }
  }
  __syncthreads();
  { // pr1 linear
    float acc[8];
    float bias = pr1_b[c];
    #pragma unroll
    for (int i = 0; i < 8; i++) acc[i] = bias;
    for (int k = 0; k < 128; k++){
      float wv = pr1_wT[k * 128 + c];
      #pragma unroll
      for (int i = 0; i < 8; i++) acc[i] += ff_s[half * 8 + i][k] * wv;
    }
    #pragma unroll
    for (int i = 0; i < 8; i++) pre_s[half * 8 + i][c] = acc[i];
  }
  __syncthreads();
  { // LN -> h
    int r = t >> 4, j = t & 15;
    float s = 0.f, ss = 0.f;
    #pragma unroll
    for (int q = 0; q < 8; q++){ float v = pre_s[r][j + q * 16]; s += v; ss += v * v; }
    #pragma unroll
    for (int m = 1; m < 16; m <<= 1){ s += __shfl_xor(s, m, 64); ss += __shfl_xor(ss, m, 64); }
    if (j == 0){ float mean = s * (1.f / 128.f); stat[r][0] = mean;
                 stat[r][1] = rsqrtf(ss * (1.f / 128.f) - mean * mean + 1e-5f); }
  }
  __syncthreads();
  {
    int r = t >> 4, j = t & 15;
    float mean = stat[r][0], rstd = stat[r][1];
    #pragma unroll
    for (int q = 0; q < 8; q++){
      int cc = j * 8 + q;
      h_s[r][cc] = fmaxf((pre_s[r][cc] - mean) * rstd * pr_g[cc] + pr_bb[cc], 0.f);
    }
  }
  __syncthreads();
  for (int item = t; item < 16 * 24; item += 256){
    int lr = item / 24, cc = item % 24;
    float accp = pr2_b[cc], accg = rg_b[cc];
    for (int k = 0; k < 128; k++){
      accp += h_s[lr][k] * pr2_wT[k * 24 + cc];
      accg += ff_s[lr][k] * rg_wT[k * 24 + cc];
    }
    float gate = 1.f / (1.f + __expf(-accg));
    int n = n0 + lr;
    float xl = x[((size_t)b * 64 + 63) * 2048 + n];
    out[((size_t)b * 24 + cc) * 2048 + n] = gate * xl + (1.f - gate) * accp;
  }
  if (blockIdx.x == 0 && t == 0) out[2 * 24 * 2048] = 1e-4f / 2048.0f;  // reg
}

extern "C" void kernel_launch(void* const* d_in, const int* in_sizes, int n_in,
                              void* d_out, int out_size, void* d_ws, size_t ws_size,
                              hipStream_t stream){
  const float* x       = (const float*)d_in[0];
  const float* tc_w    = (const float*)d_in[1];
  const float* tc_b    = (const float*)d_in[2];
  const float* tc_bn_g = (const float*)d_in[3];
  const float* tc_bn_b = (const float*)d_in[4];
  const float* fp_w    = (const float*)d_in[5];
  const float* fp_b    = (const float*)d_in[6];
  const float* fp_ln_g = (const float*)d_in[7];
  const float* fp_ln_b = (const float*)d_in[8];
  const float* q_w     = (const float*)d_in[9];
  const float* q_b     = (const float*)d_in[10];
  const float* k_w     = (const float*)d_in[11];
  const float* k_b     = (const float*)d_in[12];
  const float* v_w     = (const float*)d_in[13];
  const float* v_b     = (const float*)d_in[14];
  const float* o_w     = (const float*)d_in[15];
  const float* o_b     = (const float*)d_in[16];
  const float* adj     = (const float*)d_in[17];
  const float* s0_w    = (const float*)d_in[18];
  const float* s0_b    = (const float*)d_in[19];
  const float* s0_bn_g = (const float*)d_in[20];
  const float* s0_bn_b = (const float*)d_in[21];
  const float* s1_w    = (const float*)d_in[22];
  const float* s1_b    = (const float*)d_in[23];
  const float* s1_bn_g = (const float*)d_in[24];
  const float* s1_bn_b = (const float*)d_in[25];
  const float* fusion_w= (const float*)d_in[26];
  const float* fu_w    = (const float*)d_in[27];
  const float* fu_b    = (const float*)d_in[28];
  const float* fu_ln_g = (const float*)d_in[29];
  const float* fu_ln_b = (const float*)d_in[30];
  const float* pr1_w   = (const float*)d_in[31];
  const float* pr1_b   = (const float*)d_in[32];
  const float* pr_ln_g = (const float*)d_in[33];
  const float* pr_ln_b = (const float*)d_in[34];
  const float* pr2_w   = (const float*)d_in[35];
  const float* pr2_b   = (const float*)d_in[36];
  const float* rg_w    = (const float*)d_in[37];
  const float* rg_b    = (const float*)d_in[38];
  float* out = (float*)d_out;

  char* ws = (char*)d_ws;
  size_t off = 0;
  auto alloc = [&](size_t bytes) -> void* {
    void* p = ws + off;
    off += (bytes + 255) & ~(size_t)255;
    return p;
  };
  unsigned short* f_bf    = (unsigned short*)alloc((size_t)4096 * 2048 * 2);
  unsigned short* fpw_bf  = (unsigned short*)alloc((size_t)128 * 2048 * 2);
  unsigned short* wcat_bf = (unsigned short*)alloc((size_t)384 * 128 * 2);
  unsigned short* feats_bf= (unsigned short*)alloc((size_t)4096 * 128 * 2);
  unsigned short* q_bf    = (unsigned short*)alloc((size_t)16 * 2048 * 16 * 2);
  unsigned short* k_bf    = (unsigned short*)alloc((size_t)16 * 2048 * 16 * 2);
  unsigned short* vT_bf   = (unsigned short*)alloc((size_t)16 * 2048 * 16 * 2);
  float* go     = (float*)alloc((size_t)4096 * 128 * 4);
  float* o_wT   = (float*)alloc(128 * 128 * 4);
  float* fu_wT  = (float*)alloc(128 * 128 * 4);
  float* pr1_wT = (float*)alloc(128 * 128 * 4);
  float* s0_wT  = (float*)alloc(128 * 128 * 4);
  float* s1_wT0 = (float*)alloc(128 * 128 * 4);
  float* s1_wT1 = (float*)alloc(128 * 128 * 4);
  float* pr2_wT = (float*)alloc(128 * 24 * 4);
  float* rg_wT  = (float*)alloc(128 * 24 * 4);
  if (off > ws_size) return;  // workspace too small (should not happen)

  prep_kernel<<<512, 256, 0, stream>>>(fp_w, q_w, k_w, v_w, o_w, fu_w, pr1_w, s0_w,
                                       s1_w, pr2_w, rg_w, fpw_bf, wcat_bf, o_wT, fu_wT,
                                       pr1_wT, s0_wT, s1_wT0, s1_wT1, pr2_wT, rg_wT);
  conv_kernel<<<1024, 256, 0, stream>>>(x, tc_w, tc_b, tc_bn_g, tc_bn_b, f_bf);
  feat_kernel<<<256, 256, 0, stream>>>(f_bf, fpw_bf, fp_b, fp_ln_g, fp_ln_b, feats_bf);
  qkv_kernel<<<256, 256, 0, stream>>>(feats_bf, wcat_bf, q_b, k_b, v_b, q_bf, k_bf, vT_bf);
  attn_kernel<<<256, 256, 0, stream>>>(q_bf, k_bf, vT_bf, adj, go);
  tail_kernel<<<256, 256, 0, stream>>>(go, x, o_wT, o_b, s0_wT, s0_b, s0_bn_g, s0_bn_b,
                                       s1_wT0, s1_wT1, s1_b, s1_bn_g, s1_bn_b, fusion_w,
                                       fu_wT, fu_b, fu_ln_g, fu_ln_b, pr1_wT, pr1_b,
                                       pr_ln_g, pr_ln_b, pr2_wT, pr2_b, rg_wT, rg_b, out);
}

// Round 2
// 138.196 us; speedup vs baseline: 1.7022x; 1.7022x over previous
//
#include <hip/hip_runtime.h>

using f32x4  = __attribute__((ext_vector_type(4))) float;
using bf16x8 = __attribute__((ext_vector_type(8))) short;

#define DEV static __device__ __forceinline__

DEV unsigned short f2bf(float f){
  unsigned u = __float_as_uint(f);
  unsigned r = (u + 0x7FFFu + ((u >> 16) & 1u)) >> 16;
  return (unsigned short)r;
}

// ---------------- K0: weight prep (blocks 0..511) + temporal conv (512..1535)
__global__ __launch_bounds__(256) void prep_conv_kernel(
    const float* __restrict__ fp_w, const float* __restrict__ q_w,
    const float* __restrict__ k_w, const float* __restrict__ v_w,
    const float* __restrict__ o_w, const float* __restrict__ s0_w,
    const float* __restrict__ s1_w, const float* __restrict__ fu_w,
    const float* __restrict__ pr1_w, const float* __restrict__ pr2_w,
    const float* __restrict__ rg_w,
    unsigned short* __restrict__ fpw_bf, unsigned short* __restrict__ wcat_bf,
    float* __restrict__ o_wT, float* __restrict__ fu_wT, float* __restrict__ pr1_wT,
    float* __restrict__ s0_wT, float* __restrict__ s1_wT0, float* __restrict__ s1_wT1,
    float* __restrict__ pr2_wT, float* __restrict__ rg_wT,
    const float* __restrict__ x, const float* __restrict__ tc_w,
    const float* __restrict__ tc_b, const float* __restrict__ bn_g,
    const float* __restrict__ bn_b, unsigned short* __restrict__ f){
  if (blockIdx.x < 512){
    int i = blockIdx.x * 256 + threadIdx.x;
    const int stride = 512 * 256;
    for (int idx = i; idx < 128 * 2048; idx += stride) fpw_bf[idx] = f2bf(fp_w[idx]);
    for (int idx = i; idx < 384 * 128; idx += stride){
      int c = idx >> 7, k = idx & 127;
      float v;
      if (c < 128)      v = q_w[c * 128 + k] * 0.25f;   // fold 1/sqrt(hd)
      else if (c < 256) v = k_w[(c - 128) * 128 + k];
      else              v = v_w[(c - 256) * 128 + k];
      wcat_bf[idx] = f2bf(v);
    }
    for (int idx = i; idx < 128 * 128; idx += stride){
      int k = idx >> 7, c = idx & 127;
      o_wT[idx]   = o_w[c * 128 + k];
      fu_wT[idx]  = fu_w[c * 128 + k];
      pr1_wT[idx] = pr1_w[c * 128 + k];
      s0_wT[idx]  = s0_w[c * 128 + k];             // (o,i,1)
      s1_wT0[idx] = s1_w[(c * 128 + k) * 2 + 0];   // (o,i,2)
      s1_wT1[idx] = s1_w[(c * 128 + k) * 2 + 1];
    }
    for (int idx = i; idx < 128 * 24; idx += stride){
      int k = idx / 24, c = idx % 24;
      pr2_wT[idx] = pr2_w[c * 128 + k];
      rg_wT[idx]  = rg_w[c * 128 + k];
    }
  } else {
    int lane = threadIdx.x & 63;          // t = lane (T = 64)
    int w = threadIdx.x >> 6;
    int row = (blockIdx.x - 512) * 4 + w; // 0..4095 = b*2048+n
    int b = row >> 11, n = row & 2047;
    float xv = x[(size_t)(b * 64 + lane) * 2048 + n];
    float xm = __shfl_up(xv, 1, 64);   if (lane == 0)  xm = 0.f;
    float xp = __shfl_down(xv, 1, 64); if (lane == 63) xp = 0.f;
    const float inv = rsqrtf(1.0f + 1e-5f);
    unsigned short* frow = f + (size_t)row * 2048;
    #pragma unroll
    for (int c = 0; c < 32; c++){
      float y = xm * tc_w[c * 3 + 0] + xv * tc_w[c * 3 + 1] + xp * tc_w[c * 3 + 2] + tc_b[c];
      y = y * inv * bn_g[c] + bn_b[c];
      frow[c * 64 + lane] = f2bf(fmaxf(y, 0.f));
    }
  }
}

// ---------------- K1: feats = relu(LN(f @ fp_w^T + b)) -> bf16 (4096 x 128)
__global__ __launch_bounds__(512) void feat_kernel(
    const unsigned short* __restrict__ f, const unsigned short* __restrict__ fpw,
    const float* __restrict__ fp_b, const float* __restrict__ ln_g,
    const float* __restrict__ ln_b, unsigned short* __restrict__ feats){
  __shared__ float pre[16][128];
  __shared__ float stat[16][2];
  int t = threadIdx.x;
  int lane = t & 63, w = t >> 6;           // w = 0..7
  int l15 = lane & 15, g = lane >> 4;
  int row0 = blockIdx.x * 16;
  int c0 = w * 16;
  f32x4 acc = {0.f,0.f,0.f,0.f};
  const unsigned short* arow = f   + (size_t)(row0 + l15) * 2048 + g * 8;
  const unsigned short* bp   = fpw + (size_t)(c0 + l15) * 2048 + g * 8;
  #pragma unroll 4
  for (int k = 0; k < 2048; k += 32){
    bf16x8 a  = *(const bf16x8*)(arow + k);
    bf16x8 b0 = *(const bf16x8*)(bp + k);
    acc = __builtin_amdgcn_mfma_f32_16x16x32_bf16(a, b0, acc, 0, 0, 0);
  }
  #pragma unroll
  for (int r = 0; r < 4; r++)
    pre[g * 4 + r][c0 + l15] = acc[r] + fp_b[c0 + l15];
  __syncthreads();
  if (t < 256){
    int r = t >> 4, j = t & 15;
    float s = 0.f, ss = 0.f;
    #pragma unroll
    for (int q = 0; q < 8; q++){ float v = pre[r][j + q * 16]; s += v; ss += v * v; }
    #pragma unroll
    for (int m = 1; m < 16; m <<= 1){ s += __shfl_xor(s, m, 64); ss += __shfl_xor(ss, m, 64); }
    if (j == 0){
      float mean = s * (1.f / 128.f);
      stat[r][0] = mean;
      stat[r][1] = rsqrtf(ss * (1.f / 128.f) - mean * mean + 1e-5f);
    }
  }
  __syncthreads();
  if (t < 256){
    int r = t >> 4, j = t & 15;
    float mean = stat[r][0], rstd = stat[r][1];
    bf16x8 outv;
    #pragma unroll
    for (int q = 0; q < 8; q++){
      int c = j * 8 + q;
      float v = (pre[r][c] - mean) * rstd * ln_g[c] + ln_b[c];
      outv[q] = (short)f2bf(fmaxf(v, 0.f));
    }
    *(bf16x8*)(feats + (size_t)(row0 + r) * 128 + j * 8) = outv;
  }
}

// ---------------- K2: q/k/v projection -------------------------------------
__global__ __launch_bounds__(256) void qkv_kernel(
    const unsigned short* __restrict__ feats, const unsigned short* __restrict__ wcat,
    const float* __restrict__ q_b, const float* __restrict__ k_b,
    const float* __restrict__ v_b, unsigned short* __restrict__ qo,
    unsigned short* __restrict__ ko, unsigned short* __restrict__ vT){
  int t = threadIdx.x, lane = t & 63, w = t >> 6;
  int l15 = lane & 15, g = lane >> 4;
  int row0 = blockIdx.x * 16;
  int c0 = w * 96;
  f32x4 acc[6];
  #pragma unroll
  for (int i = 0; i < 6; i++) acc[i] = (f32x4){0.f,0.f,0.f,0.f};
  const unsigned short* arow = feats + (size_t)(row0 + l15) * 128 + g * 8;
  #pragma unroll
  for (int k = 0; k < 128; k += 32){
    bf16x8 a = *(const bf16x8*)(arow + k);
    #pragma unroll
    for (int ni = 0; ni < 6; ni++){
      bf16x8 bb = *(const bf16x8*)(wcat + (size_t)(c0 + ni * 16 + l15) * 128 + g * 8 + k);
      acc[ni] = __builtin_amdgcn_mfma_f32_16x16x32_bf16(a, bb, acc[ni], 0, 0, 0);
    }
  }
  #pragma unroll
  for (int ni = 0; ni < 6; ni++){
    int c = c0 + ni * 16 + l15;
    int mat = c >> 7, cm = c & 127;
    int h = cm >> 4, d = cm & 15;
    float bias = (mat == 0) ? q_b[cm] * 0.25f : (mat == 1 ? k_b[cm] : v_b[cm]);
    #pragma unroll
    for (int r = 0; r < 4; r++){
      int row = row0 + g * 4 + r;
      int b = row >> 11, n = row & 2047;
      unsigned short bv = f2bf(acc[ni][r] + bias);
      int bh = b * 8 + h;
      if (mat == 0)      qo[((size_t)bh * 2048 + n) * 16 + d] = bv;
      else if (mat == 1) ko[((size_t)bh * 2048 + n) * 16 + d] = bv;
      else               vT[((size_t)bh * 16 + d) * 2048 + n] = bv;
    }
  }
}

// ---------------- K3: fused attention, m-split across 4 waves --------------
__global__ __launch_bounds__(256) void attn_kernel(
    const unsigned short* __restrict__ qo, const unsigned short* __restrict__ ko,
    const unsigned short* __restrict__ vT, const float* __restrict__ adj,
    float* __restrict__ go){
  __shared__ unsigned short Pls[4][1024];
  __shared__ float adjs[4][16][68];
  __shared__ float red_acc[4][2][16][16];
  __shared__ float red_rs[4][2][16];
  int t = threadIdx.x, lane = t & 63, w = t >> 6;
  int l15 = lane & 15, g = lane >> 4;
  int h = blockIdx.x >> 7;                 // 0..7
  int row0 = (blockIdx.x & 127) * 16;      // q-row tile of 16
  const bf16x8 zf = {0,0,0,0,0,0,0,0};
  bf16x8 qf[2];
  #pragma unroll
  for (int b = 0; b < 2; b++){
    if (g < 2) qf[b] = *(const bf16x8*)(qo + ((size_t)(b * 8 + h) * 2048 + row0 + l15) * 16 + g * 8);
    else       qf[b] = zf;
  }
  f32x4 accv[2] = {{0.f,0.f,0.f,0.f},{0.f,0.f,0.f,0.f}};
  float rs[2][4] = {{0,0,0,0},{0,0,0,0}};
  const float* adjbase = adj + ((size_t)h * 2048 + row0) * 2048;
  unsigned short* P = Pls[w];
  float (*A)[68] = adjs[w];
  const int mbeg = w * 512;
  for (int m0 = mbeg; m0 < mbeg + 512; m0 += 64){
    // stage 16x64 adj tile via float4 (coalesced, 4 VMEM instrs)
    #pragma unroll
    for (int it = 0; it < 4; it++){
      int idx = it * 64 + lane;
      int rr = idx >> 4, c4 = (idx & 15) << 2;
      *(f32x4*)(&A[rr][c4]) = *(const f32x4*)(adjbase + (size_t)rr * 2048 + m0 + c4);
    }
    #pragma unroll
    for (int b = 0; b < 2; b++){
      int bh = b * 8 + h;
      const unsigned short* kbase = ko + (size_t)bh * 2048 * 16;
      f32x4 sf[4];
      #pragma unroll
      for (int s = 0; s < 4; s++){
        bf16x8 kf;
        if (g < 2) kf = *(const bf16x8*)(kbase + (size_t)(m0 + s * 16 + l15) * 16 + g * 8);
        else       kf = zf;
        f32x4 z4 = {0.f,0.f,0.f,0.f};
        sf[s] = __builtin_amdgcn_mfma_f32_16x16x32_bf16(qf[b], kf, z4, 0, 0, 0);
      }
      #pragma unroll
      for (int s = 0; s < 4; s++){
        #pragma unroll
        for (int r = 0; r < 4; r++){
          int rowl = g * 4 + r;
          float p = __expf(sf[s][r] + A[rowl][s * 16 + l15]);   // scores tiny: no-max softmax
          rs[b][r] += p;
          int col = s * 16 + l15;
          int chunk = col >> 3;
          P[rowl * 64 + (((chunk ^ (rowl & 7)) << 3) | (col & 7))] = f2bf(p);
        }
      }
      const unsigned short* vbase = vT + (size_t)bh * 16 * 2048;
      #pragma unroll
      for (int half = 0; half < 2; half++){
        int chunk = half * 4 + g;
        bf16x8 af = *(const bf16x8*)(P + l15 * 64 + ((chunk ^ (l15 & 7)) << 3));
        bf16x8 vf = *(const bf16x8*)(vbase + (size_t)l15 * 2048 + m0 + half * 32 + g * 8);
        accv[b] = __builtin_amdgcn_mfma_f32_16x16x32_bf16(af, vf, accv[b], 0, 0, 0);
      }
    }
  }
  // cross-wave reduction of partial PV and partial row-sums
  #pragma unroll
  for (int b = 0; b < 2; b++){
    #pragma unroll
    for (int r = 0; r < 4; r++){
      float s = rs[b][r];
      #pragma unroll
      for (int m = 1; m < 16; m <<= 1) s += __shfl_xor(s, m, 64);
      red_acc[w][b][g * 4 + r][l15] = accv[b][r];
      if (l15 == 0) red_rs[w][b][g * 4 + r] = s;
    }
  }
  __syncthreads();
  for (int i = t; i < 512; i += 256){
    int b = i >> 8, row = (i >> 4) & 15, col = i & 15;
    float v = 0.f, d = 0.f;
    #pragma unroll
    for (int ww = 0; ww < 4; ww++){ v += red_acc[ww][b][row][col]; d += red_rs[ww][b][row]; }
    go[((size_t)b * 2048 + row0 + row) * 128 + h * 16 + col] = v / d;
  }
}

// ---------------- K4: o-proj + s0/s1 convs + interp + fusion + tail --------
__global__ __launch_bounds__(512) void tail_kernel(
    const float* __restrict__ go, const float* __restrict__ x,
    const float* __restrict__ o_wT, const float* __restrict__ o_b,
    const float* __restrict__ s0_wT, const float* __restrict__ s0_b,
    const float* __restrict__ s0_g, const float* __restrict__ s0_bb,
    const float* __restrict__ s1_wT0, const float* __restrict__ s1_wT1,
    const float* __restrict__ s1_b, const float* __restrict__ s1_g,
    const float* __restrict__ s1_bb, const float* __restrict__ fw,
    const float* __restrict__ fu_wT, const float* __restrict__ fu_b,
    const float* __restrict__ fu_g, const float* __restrict__ fu_bb,
    const float* __restrict__ pr1_wT, const float* __restrict__ pr1_b,
    const float* __restrict__ pr_g, const float* __restrict__ pr_bb,
    const float* __restrict__ pr2_wT, const float* __restrict__ pr2_b,
    const float* __restrict__ rg_wT, const float* __restrict__ rg_b,
    float* __restrict__ out){
  __shared__ float go_s[20][128];
  __shared__ float gf_s[21][128];
  __shared__ float f1_s[17][128];
  __shared__ float fu_in[16][128];
  __shared__ float pre_s[16][128];
  __shared__ float ff_s[16][128];
  __shared__ float h_s[16][128];
  __shared__ float stat[16][2];
  int t = threadIdx.x;
  int b = blockIdx.x >> 7;
  int n0 = (blockIdx.x & 127) * 16;
  for (int e = t; e < 20 * 128; e += 512){
    int lr = e >> 7, cc = e & 127;
    int gn = n0 - 1 + lr;
    go_s[lr][cc] = (lr < 18 && gn >= 0 && gn < 2048) ? go[((size_t)b * 2048 + gn) * 128 + cc] : 0.f;
  }
  __syncthreads();
  int c = t & 127, q4 = t >> 7;   // q4 = 0..3, rows strided i*4+q4
  const float bninv = rsqrtf(1.0f + 1e-5f);
  { // gf = go @ o_w^T + o_b  (rows 0..17 valid incl halo; zero outside)
    float acc[5];
    float bias = o_b[c];
    #pragma unroll
    for (int i = 0; i < 5; i++) acc[i] = bias;
    for (int k = 0; k < 128; k++){
      float wv = o_wT[k * 128 + c];
      #pragma unroll
      for (int i = 0; i < 5; i++) acc[i] += go_s[i * 4 + q4][k] * wv;
    }
    #pragma unroll
    for (int i = 0; i < 5; i++){
      int lr = i * 4 + q4;
      int gn = n0 - 1 + lr;
      gf_s[lr][c] = (lr < 18 && gn >= 0 && gn < 2048) ? acc[i] : 0.f;
    }
    if (t < 128) gf_s[20][t] = 0.f;
  }
  __syncthreads();
  { // f1[lr] = relu(bn1(w0*gf[lr-1+..] conv)), rows 0..16
    float acc[5];
    float bias = s1_b[c];
    #pragma unroll
    for (int i = 0; i < 5; i++) acc[i] = bias;
    for (int k = 0; k < 128; k++){
      float w0 = s1_wT0[k * 128 + c], w1 = s1_wT1[k * 128 + c];
      #pragma unroll
      for (int i = 0; i < 5; i++)
        acc[i] += gf_s[i * 4 + q4][k] * w0 + gf_s[i * 4 + q4 + 1][k] * w1;
    }
    float sc = s1_g[c] * bninv, bb2 = s1_bb[c];
    #pragma unroll
    for (int i = 0; i < 5; i++){
      int lr = i * 4 + q4;
      if (lr < 17) f1_s[lr][c] = fmaxf(acc[i] * sc + bb2, 0.f);
    }
  }
  __syncthreads();
  { // fused = a0*f0 + a1*interp(f1), rows 0..15
    float acc[4];
    float bias = s0_b[c];
    #pragma unroll
    for (int i = 0; i < 4; i++) acc[i] = bias;
    for (int k = 0; k < 128; k++){
      float wv = s0_wT[k * 128 + c];
      #pragma unroll
      for (int i = 0; i < 4; i++) acc[i] += gf_s[i * 4 + q4 + 1][k] * wv;
    }
    float e0 = __expf(fw[0]), e1 = __expf(fw[1]);
    float a0 = e0 / (e0 + e1), a1 = e1 / (e0 + e1);
    float sc = s0_g[c] * bninv, bb2 = s0_bb[c];
    #pragma unroll
    for (int i = 0; i < 4; i++){
      int lr = i * 4 + q4;
      int n = n0 + lr;
      float f0 = fmaxf(acc[i] * sc + bb2, 0.f);
      float wn = (n + 0.5f) * (1.0f / 2048.0f);
      fu_in[lr][c] = a0 * f0 + a1 * ((1.f - wn) * f1_s[lr][c] + wn * f1_s[lr + 1][c]);
    }
  }
  __syncthreads();
  { // fu linear
    float acc[4];
    float bias = fu_b[c];
    #pragma unroll
    for (int i = 0; i < 4; i++) acc[i] = bias;
    for (int k = 0; k < 128; k++){
      float wv = fu_wT[k * 128 + c];
      #pragma unroll
      for (int i = 0; i < 4; i++) acc[i] += fu_in[i * 4 + q4][k] * wv;
    }
    #pragma unroll
    for (int i = 0; i < 4; i++) pre_s[i * 4 + q4][c] = acc[i];
  }
  __syncthreads();
  if (t < 256){ // LN stats
    int r = t >> 4, j = t & 15;
    float s = 0.f, ss = 0.f;
    #pragma unroll
    for (int q = 0; q < 8; q++){ float v = pre_s[r][j + q * 16]; s += v; ss += v * v; }
    #pragma unroll
    for (int m = 1; m < 16; m <<= 1){ s += __shfl_xor(s, m, 64); ss += __shfl_xor(ss, m, 64); }
    if (j == 0){ float mean = s * (1.f / 128.f); stat[r][0] = mean;
                 stat[r][1] = rsqrtf(ss * (1.f / 128.f) - mean * mean + 1e-5f); }
  }
  __syncthreads();
  if (t < 256){
    int r = t >> 4, j = t & 15;
    float mean = stat[r][0], rstd = stat[r][1];
    #pragma unroll
    for (int q = 0; q < 8; q++){
      int cc = j * 8 + q;
      ff_s[r][cc] = fmaxf((pre_s[r][cc] - mean) * rstd * fu_g[cc] + fu_bb[cc], 0.f);
    }
  }
  __syncthreads();
  { // pr1 linear
    float acc[4];
    float bias = pr1_b[c];
    #pragma unroll
    for (int i = 0; i < 4; i++) acc[i] = bias;
    for (int k = 0; k < 128; k++){
      float wv = pr1_wT[k * 128 + c];
      #pragma unroll
      for (int i = 0; i < 4; i++) acc[i] += ff_s[i * 4 + q4][k] * wv;
    }
    #pragma unroll
    for (int i = 0; i < 4; i++) pre_s[i * 4 + q4][c] = acc[i];
  }
  __syncthreads();
  if (t < 256){ // LN stats
    int r = t >> 4, j = t & 15;
    float s = 0.f, ss = 0.f;
    #pragma unroll
    for (int q = 0; q < 8; q++){ float v = pre_s[r][j + q * 16]; s += v; ss += v * v; }
    #pragma unroll
    for (int m = 1; m < 16; m <<= 1){ s += __shfl_xor(s, m, 64); ss += __shfl_xor(ss, m, 64); }
    if (j == 0){ float mean = s * (1.f / 128.f); stat[r][0] = mean;
                 stat[r][1] = rsqrtf(ss * (1.f / 128.f) - mean * mean + 1e-5f); }
  }
  __syncthreads();
  if (t < 256){
    int r = t >> 4, j = t & 15;
    float mean = stat[r][0], rstd = stat[r][1];
    #pragma unroll
    for (int q = 0; q < 8; q++){
      int cc = j * 8 + q;
      h_s[r][cc] = fmaxf((pre_s[r][cc] - mean) * rstd * pr_g[cc] + pr_bb[cc], 0.f);
    }
  }
  __syncthreads();
  if (t < 384){
    int lr = t / 24, cc = t % 24;
    float accp = pr2_b[cc], accg = rg_b[cc];
    for (int k = 0; k < 128; k++){
      accp += h_s[lr][k] * pr2_wT[k * 24 + cc];
      accg += ff_s[lr][k] * rg_wT[k * 24 + cc];
    }
    float gate = 1.f / (1.f + __expf(-accg));
    int n = n0 + lr;
    float xl = x[((size_t)b * 64 + 63) * 2048 + n];
    out[((size_t)b * 24 + cc) * 2048 + n] = gate * xl + (1.f - gate) * accp;
  }
  if (blockIdx.x == 0 && t == 0) out[2 * 24 * 2048] = 1e-4f / 2048.0f;  // reg
}

extern "C" void kernel_launch(void* const* d_in, const int* in_sizes, int n_in,
                              void* d_out, int out_size, void* d_ws, size_t ws_size,
                              hipStream_t stream){
  const float* x       = (const float*)d_in[0];
  const float* tc_w    = (const float*)d_in[1];
  const float* tc_b    = (const float*)d_in[2];
  const float* tc_bn_g = (const float*)d_in[3];
  const float* tc_bn_b = (const float*)d_in[4];
  const float* fp_w    = (const float*)d_in[5];
  const float* fp_b    = (const float*)d_in[6];
  const float* fp_ln_g = (const float*)d_in[7];
  const float* fp_ln_b = (const float*)d_in[8];
  const float* q_w     = (const float*)d_in[9];
  const float* q_b     = (const float*)d_in[10];
  const float* k_w     = (const float*)d_in[11];
  const float* k_b     = (const float*)d_in[12];
  const float* v_w     = (const float*)d_in[13];
  const float* v_b     = (const float*)d_in[14];
  const float* o_w     = (const float*)d_in[15];
  const float* o_b     = (const float*)d_in[16];
  const float* adj     = (const float*)d_in[17];
  const float* s0_w    = (const float*)d_in[18];
  const float* s0_b    = (const float*)d_in[19];
  const float* s0_bn_g = (const float*)d_in[20];
  const float* s0_bn_b = (const float*)d_in[21];
  const float* s1_w    = (const float*)d_in[22];
  const float* s1_b    = (const float*)d_in[23];
  const float* s1_bn_g = (const float*)d_in[24];
  const float* s1_bn_b = (const float*)d_in[25];
  const float* fusion_w= (const float*)d_in[26];
  const float* fu_w    = (const float*)d_in[27];
  const float* fu_b    = (const float*)d_in[28];
  const float* fu_ln_g = (const float*)d_in[29];
  const float* fu_ln_b = (const float*)d_in[30];
  const float* pr1_w   = (const float*)d_in[31];
  const float* pr1_b   = (const float*)d_in[32];
  const float* pr_ln_g = (const float*)d_in[33];
  const float* pr_ln_b = (const float*)d_in[34];
  const float* pr2_w   = (const float*)d_in[35];
  const float* pr2_b   = (const float*)d_in[36];
  const float* rg_w    = (const float*)d_in[37];
  const float* rg_b    = (const float*)d_in[38];
  float* out = (float*)d_out;

  char* ws = (char*)d_ws;
  size_t off = 0;
  auto alloc = [&](size_t bytes) -> void* {
    void* p = ws + off;
    off += (bytes + 255) & ~(size_t)255;
    return p;
  };
  unsigned short* f_bf    = (unsigned short*)alloc((size_t)4096 * 2048 * 2);
  unsigned short* fpw_bf  = (unsigned short*)alloc((size_t)128 * 2048 * 2);
  unsigned short* wcat_bf = (unsigned short*)alloc((size_t)384 * 128 * 2);
  unsigned short* feats_bf= (unsigned short*)alloc((size_t)4096 * 128 * 2);
  unsigned short* q_bf    = (unsigned short*)alloc((size_t)16 * 2048 * 16 * 2);
  unsigned short* k_bf    = (unsigned short*)alloc((size_t)16 * 2048 * 16 * 2);
  unsigned short* vT_bf   = (unsigned short*)alloc((size_t)16 * 2048 * 16 * 2);
  float* go     = (float*)alloc((size_t)4096 * 128 * 4);
  float* o_wT   = (float*)alloc(128 * 128 * 4);
  float* fu_wT  = (float*)alloc(128 * 128 * 4);
  float* pr1_wT = (float*)alloc(128 * 128 * 4);
  float* s0_wT  = (float*)alloc(128 * 128 * 4);
  float* s1_wT0 = (float*)alloc(128 * 128 * 4);
  float* s1_wT1 = (float*)alloc(128 * 128 * 4);
  float* pr2_wT = (float*)alloc(128 * 24 * 4);
  float* rg_wT  = (float*)alloc(128 * 24 * 4);
  if (off > ws_size) return;  // workspace too small (should not happen)

  prep_conv_kernel<<<1536, 256, 0, stream>>>(fp_w, q_w, k_w, v_w, o_w, s0_w, s1_w,
                                             fu_w, pr1_w, pr2_w, rg_w, fpw_bf, wcat_bf,
                                             o_wT, fu_wT, pr1_wT, s0_wT, s1_wT0, s1_wT1,
                                             pr2_wT, rg_wT,
                                             x, tc_w, tc_b, tc_bn_g, tc_bn_b, f_bf);
  feat_kernel<<<256, 512, 0, stream>>>(f_bf, fpw_bf, fp_b, fp_ln_g, fp_ln_b, feats_bf);
  qkv_kernel<<<256, 256, 0, stream>>>(feats_bf, wcat_bf, q_b, k_b, v_b, q_bf, k_bf, vT_bf);
  attn_kernel<<<1024, 256, 0, stream>>>(q_bf, k_bf, vT_bf, adj, go);
  tail_kernel<<<256, 512, 0, stream>>>(go, x, o_wT, o_b, s0_wT, s0_b, s0_bn_g, s0_bn_b,
                                       s1_wT0, s1_wT1, s1_b, s1_bn_g, s1_bn_b, fusion_w,
                                       fu_wT, fu_b, fu_ln_g, fu_ln_b, pr1_wT, pr1_b,
                                       pr_ln_g, pr_ln_b, pr2_wT, pr2_b, rg_wT, rg_b, out);
}